// Round 3
// baseline (158.238 us; speedup 1.0000x reference)
//
#include <hip/hip_runtime.h>
#include <math.h>

#define T_TOK 4096
#define D_DIM 2048
#define E_EXP 8

typedef float f32x4 __attribute__((ext_vector_type(4)));

struct TokRec { int e0, e1; float g0, g1; };

// ---------------- Kernel 1: gating (logits -> softmax -> top2) --------------
// One wave (64 lanes) per token. fp64 accumulation so routing decisions match
// the reference exactly (a single flipped top-2 breaks the tags output).
__global__ __launch_bounds__(256) void gating_kernel(const float* __restrict__ x,
                                                     const float* __restrict__ Wg,
                                                     TokRec* __restrict__ recs) {
    const int wave = threadIdx.x >> 6;
    const int lane = threadIdx.x & 63;
    const int t = blockIdx.x * 4 + wave;
    const float* xr = x + (size_t)t * D_DIM;

    double acc[E_EXP];
#pragma unroll
    for (int e = 0; e < E_EXP; ++e) acc[e] = 0.0;

#pragma unroll
    for (int i = 0; i < D_DIM / 256; ++i) {
        const int d = i * 256 + lane * 4;
        const float4 xv = *reinterpret_cast<const float4*>(xr + d);
#pragma unroll
        for (int j = 0; j < 4; ++j) {
            const float xs = (j == 0) ? xv.x : (j == 1) ? xv.y : (j == 2) ? xv.z : xv.w;
            const float4 w0 = *reinterpret_cast<const float4*>(Wg + (size_t)(d + j) * E_EXP);
            const float4 w1 = *reinterpret_cast<const float4*>(Wg + (size_t)(d + j) * E_EXP + 4);
            acc[0] += (double)xs * (double)w0.x;
            acc[1] += (double)xs * (double)w0.y;
            acc[2] += (double)xs * (double)w0.z;
            acc[3] += (double)xs * (double)w0.w;
            acc[4] += (double)xs * (double)w1.x;
            acc[5] += (double)xs * (double)w1.y;
            acc[6] += (double)xs * (double)w1.z;
            acc[7] += (double)xs * (double)w1.w;
        }
    }
#pragma unroll
    for (int e = 0; e < E_EXP; ++e) {
        double v = acc[e];
#pragma unroll
        for (int off = 32; off > 0; off >>= 1) v += __shfl_xor(v, off, 64);
        acc[e] = v;
    }
    if (lane == 0) {
        double m = acc[0];
#pragma unroll
        for (int e = 1; e < E_EXP; ++e) m = (acc[e] > m) ? acc[e] : m;
        double Z = 0.0;
#pragma unroll
        for (int e = 0; e < E_EXP; ++e) Z += exp(acc[e] - m);
        int e0 = 0;
#pragma unroll
        for (int e = 1; e < E_EXP; ++e) if (acc[e] > acc[e0]) e0 = e;
        int e1 = (e0 == 0) ? 1 : 0;
#pragma unroll
        for (int e = 0; e < E_EXP; ++e) if (e != e0 && acc[e] > acc[e1]) e1 = e;
        TokRec r;
        r.e0 = e0; r.e1 = e1;
        r.g0 = (float)(exp(acc[e0] - m) / Z);
        r.g1 = (float)(exp(acc[e1] - m) / Z);
        recs[t] = r;
    }
}

// ---------------- Kernel 2: single-block scan -> positions ------------------
// Filled slots for expert e are exactly [0, loads[e]); scatter derives
// emptiness from loads, so no srcmap init needed. Scan writes only the 8192
// filled (src, gate) pairs + per-expert loads.
__global__ __launch_bounds__(256) void scan_kernel(const TokRec* __restrict__ recs,
                                                   int2* __restrict__ smap,
                                                   int* __restrict__ loads_i,
                                                   float* __restrict__ loads_out) {
    __shared__ uint4 sb[256];
    __shared__ int offlds[256 * 8];
    const int tid = threadIdx.x;

    // local counts as 8x8-bit fields (max 32 per field, no overflow)
    const int t0 = tid * 16;
    unsigned long long c = 0ULL;
    TokRec rl[16];
    for (int k = 0; k < 16; ++k) {
        rl[k] = recs[t0 + k];
        c += 1ULL << (rl[k].e0 * 8);
        c += 1ULL << (rl[k].e1 * 8);
    }
    uint4 v;
    v.x = (unsigned)((c       ) & 0xFF) | ((unsigned)((c >>  8) & 0xFF) << 16);
    v.y = (unsigned)((c >> 16 ) & 0xFF) | ((unsigned)((c >> 24) & 0xFF) << 16);
    v.z = (unsigned)((c >> 32 ) & 0xFF) | ((unsigned)((c >> 40) & 0xFF) << 16);
    v.w = (unsigned)((c >> 48 ) & 0xFF) | ((unsigned)((c >> 56) & 0xFF) << 16);
    const uint4 own = v;
    sb[tid] = v;
    for (int d = 1; d < 256; d <<= 1) {
        __syncthreads();
        uint4 o = make_uint4(0u, 0u, 0u, 0u);
        if (tid >= d) o = sb[tid - d];
        __syncthreads();
        v.x += o.x; v.y += o.y; v.z += o.z; v.w += o.w;
        sb[tid] = v;
    }
    __syncthreads();
    const uint4 tot = sb[255];

    offlds[tid * 8 + 0] = (int)((v.x - own.x) & 0xFFFF);
    offlds[tid * 8 + 1] = (int)((v.x - own.x) >> 16);
    offlds[tid * 8 + 2] = (int)((v.y - own.y) & 0xFFFF);
    offlds[tid * 8 + 3] = (int)((v.y - own.y) >> 16);
    offlds[tid * 8 + 4] = (int)((v.z - own.z) & 0xFFFF);
    offlds[tid * 8 + 5] = (int)((v.z - own.z) >> 16);
    offlds[tid * 8 + 6] = (int)((v.w - own.w) & 0xFFFF);
    offlds[tid * 8 + 7] = (int)((v.w - own.w) >> 16);

    if (tid < 8) {
        unsigned comp = (tid < 2) ? tot.x : (tid < 4) ? tot.y : (tid < 6) ? tot.z : tot.w;
        unsigned val = (tid & 1) ? (comp >> 16) : (comp & 0xFFFF);
        loads_i[tid] = (int)val;
        loads_out[tid] = (float)val;   // loads output written as float32
    }

    const int obase = tid * 8;
    for (int k = 0; k < 16; ++k) {
        const TokRec r = rl[k];
        const int tok = t0 + k;
        int d0 = offlds[obase + r.e0]++;
        smap[r.e0 * T_TOK + d0] = make_int2(tok, __float_as_int(r.g0));
        int d1 = offlds[obase + r.e1]++;
        smap[r.e1 * T_TOK + d1] = make_int2(tok, __float_as_int(r.g1));
    }
}

// ---------------- Kernel 3: full out_data fill + tags -----------------------
// 4 rows per block; 256 threads x 8 floats = one 2048-wide row per iteration.
// Nontemporal stores: out_data is 256 MB streamed once, never re-read.
__global__ __launch_bounds__(256) void scatter_kernel(const float* __restrict__ x,
                                                      const int2* __restrict__ smap,
                                                      const int* __restrict__ loads_i,
                                                      float* __restrict__ out_data,
                                                      float* __restrict__ out_tags) {
    const int tid = threadIdx.x;
    const int row0 = blockIdx.x * 4;
    const int base = tid * 8;
#pragma unroll
    for (int k = 0; k < 4; ++k) {
        const int row = row0 + k;
        const int e = row >> 12;
        const int r = row & (T_TOK - 1);
        float* orow = out_data + (size_t)row * D_DIM;
        if (r >= loads_i[e]) {
            if (tid == 0) out_tags[row] = -1.0f;
            const f32x4 z = {0.f, 0.f, 0.f, 0.f};
            __builtin_nontemporal_store(z, reinterpret_cast<f32x4*>(orow + base));
            __builtin_nontemporal_store(z, reinterpret_cast<f32x4*>(orow + base + 4));
        } else {
            const int2 sg = smap[row];
            const int src = sg.x;
            const float g = __int_as_float(sg.y);
            if (tid == 0) out_tags[row] = (float)src;
            const float* xr = x + (size_t)src * D_DIM;
            f32x4 a = *reinterpret_cast<const f32x4*>(xr + base);
            f32x4 b = *reinterpret_cast<const f32x4*>(xr + base + 4);
            a *= g;
            b *= g;
            __builtin_nontemporal_store(a, reinterpret_cast<f32x4*>(orow + base));
            __builtin_nontemporal_store(b, reinterpret_cast<f32x4*>(orow + base + 4));
        }
    }
}

extern "C" void kernel_launch(void* const* d_in, const int* in_sizes, int n_in,
                              void* d_out, int out_size, void* d_ws, size_t ws_size,
                              hipStream_t stream) {
    const float* x  = (const float*)d_in[0];
    const float* Wg = (const float*)d_in[1];

    float* out       = (float*)d_out;
    float* out_data  = out;
    float* out_tags  = out + (size_t)E_EXP * T_TOK * D_DIM;
    float* out_loads = out_tags + E_EXP * T_TOK;

    char* ws = (char*)d_ws;
    TokRec* recs    = (TokRec*)ws;                         // 64 KiB
    int2*   smap    = (int2*)(ws + 65536);                 // 256 KiB
    int*    loads_i = (int*)(ws + 65536 + 262144);         // 32 B

    gating_kernel<<<T_TOK / 4, 256, 0, stream>>>(x, Wg, recs);
    scan_kernel<<<1, 256, 0, stream>>>(recs, smap, loads_i, out_loads);
    scatter_kernel<<<E_EXP * T_TOK / 4, 256, 0, stream>>>(x, smap, loads_i, out_data, out_tags);
}

// Round 4
// 93.518 us; speedup vs baseline: 1.6920x; 1.6920x over previous
//
#include <hip/hip_runtime.h>
#include <math.h>

#define T_TOK 4096
#define D_DIM 2048
#define E_EXP 8

typedef float f32x4 __attribute__((ext_vector_type(4)));

struct TokRec { int e0, e1; float g0, g1; };

// ---------------- Kernel 1: gating (logits -> softmax -> top2) --------------
// One wave (64 lanes) per token. fp64 accumulation so routing decisions match
// the reference exactly (a single flipped top-2 breaks the tags output).
__global__ __launch_bounds__(256) void gating_kernel(const float* __restrict__ x,
                                                     const float* __restrict__ Wg,
                                                     TokRec* __restrict__ recs) {
    const int wave = threadIdx.x >> 6;
    const int lane = threadIdx.x & 63;
    const int t = blockIdx.x * 4 + wave;
    const float* xr = x + (size_t)t * D_DIM;

    double acc[E_EXP];
#pragma unroll
    for (int e = 0; e < E_EXP; ++e) acc[e] = 0.0;

#pragma unroll
    for (int i = 0; i < D_DIM / 256; ++i) {
        const int d = i * 256 + lane * 4;
        const float4 xv = *reinterpret_cast<const float4*>(xr + d);
#pragma unroll
        for (int j = 0; j < 4; ++j) {
            const float xs = (j == 0) ? xv.x : (j == 1) ? xv.y : (j == 2) ? xv.z : xv.w;
            const float4 w0 = *reinterpret_cast<const float4*>(Wg + (size_t)(d + j) * E_EXP);
            const float4 w1 = *reinterpret_cast<const float4*>(Wg + (size_t)(d + j) * E_EXP + 4);
            acc[0] += (double)xs * (double)w0.x;
            acc[1] += (double)xs * (double)w0.y;
            acc[2] += (double)xs * (double)w0.z;
            acc[3] += (double)xs * (double)w0.w;
            acc[4] += (double)xs * (double)w1.x;
            acc[5] += (double)xs * (double)w1.y;
            acc[6] += (double)xs * (double)w1.z;
            acc[7] += (double)xs * (double)w1.w;
        }
    }
#pragma unroll
    for (int e = 0; e < E_EXP; ++e) {
        double v = acc[e];
#pragma unroll
        for (int off = 32; off > 0; off >>= 1) v += __shfl_xor(v, off, 64);
        acc[e] = v;
    }
    if (lane == 0) {
        double m = acc[0];
#pragma unroll
        for (int e = 1; e < E_EXP; ++e) m = (acc[e] > m) ? acc[e] : m;
        double Z = 0.0;
#pragma unroll
        for (int e = 0; e < E_EXP; ++e) Z += exp(acc[e] - m);
        int e0 = 0;
#pragma unroll
        for (int e = 1; e < E_EXP; ++e) if (acc[e] > acc[e0]) e0 = e;
        int e1 = (e0 == 0) ? 1 : 0;
#pragma unroll
        for (int e = 0; e < E_EXP; ++e) if (e != e0 && acc[e] > acc[e1]) e1 = e;
        TokRec r;
        r.e0 = e0; r.e1 = e1;
        r.g0 = (float)(exp(acc[e0] - m) / Z);
        r.g1 = (float)(exp(acc[e1] - m) / Z);
        recs[t] = r;
    }
}

// ---------------- Kernel 2: single-block scan -> positions ------------------
// Filled slots for expert e are exactly [0, loads[e]); scatter derives
// emptiness from loads, so no srcmap init needed. Scan writes only the 8192
// filled (src, gate) pairs + per-expert loads.
__global__ __launch_bounds__(256) void scan_kernel(const TokRec* __restrict__ recs,
                                                   int2* __restrict__ smap,
                                                   int* __restrict__ loads_i,
                                                   float* __restrict__ loads_out) {
    __shared__ uint4 sb[256];
    __shared__ int offlds[256 * 8];
    const int tid = threadIdx.x;

    // local counts as 8x8-bit fields (max 32 per field, no overflow)
    const int t0 = tid * 16;
    unsigned long long c = 0ULL;
    TokRec rl[16];
    for (int k = 0; k < 16; ++k) {
        rl[k] = recs[t0 + k];
        c += 1ULL << (rl[k].e0 * 8);
        c += 1ULL << (rl[k].e1 * 8);
    }
    uint4 v;
    v.x = (unsigned)((c       ) & 0xFF) | ((unsigned)((c >>  8) & 0xFF) << 16);
    v.y = (unsigned)((c >> 16 ) & 0xFF) | ((unsigned)((c >> 24) & 0xFF) << 16);
    v.z = (unsigned)((c >> 32 ) & 0xFF) | ((unsigned)((c >> 40) & 0xFF) << 16);
    v.w = (unsigned)((c >> 48 ) & 0xFF) | ((unsigned)((c >> 56) & 0xFF) << 16);
    const uint4 own = v;
    sb[tid] = v;
    for (int d = 1; d < 256; d <<= 1) {
        __syncthreads();
        uint4 o = make_uint4(0u, 0u, 0u, 0u);
        if (tid >= d) o = sb[tid - d];
        __syncthreads();
        v.x += o.x; v.y += o.y; v.z += o.z; v.w += o.w;
        sb[tid] = v;
    }
    __syncthreads();
    const uint4 tot = sb[255];

    offlds[tid * 8 + 0] = (int)((v.x - own.x) & 0xFFFF);
    offlds[tid * 8 + 1] = (int)((v.x - own.x) >> 16);
    offlds[tid * 8 + 2] = (int)((v.y - own.y) & 0xFFFF);
    offlds[tid * 8 + 3] = (int)((v.y - own.y) >> 16);
    offlds[tid * 8 + 4] = (int)((v.z - own.z) & 0xFFFF);
    offlds[tid * 8 + 5] = (int)((v.z - own.z) >> 16);
    offlds[tid * 8 + 6] = (int)((v.w - own.w) & 0xFFFF);
    offlds[tid * 8 + 7] = (int)((v.w - own.w) >> 16);

    if (tid < 8) {
        unsigned comp = (tid < 2) ? tot.x : (tid < 4) ? tot.y : (tid < 6) ? tot.z : tot.w;
        unsigned val = (tid & 1) ? (comp >> 16) : (comp & 0xFFFF);
        loads_i[tid] = (int)val;
        loads_out[tid] = (float)val;   // loads output written as float32
    }

    const int obase = tid * 8;
    for (int k = 0; k < 16; ++k) {
        const TokRec r = rl[k];
        const int tok = t0 + k;
        int d0 = offlds[obase + r.e0]++;
        smap[r.e0 * T_TOK + d0] = make_int2(tok, __float_as_int(r.g0));
        int d1 = offlds[obase + r.e1]++;
        smap[r.e1 * T_TOK + d1] = make_int2(tok, __float_as_int(r.g1));
    }
}

// ---------------- Kernel 3: full out_data fill + tags -----------------------
// 4 rows per block; 256 threads x 8 floats = one 2048-wide row per iteration.
// PLAIN vector stores: R3 showed __builtin_nontemporal_store regressed the
// streaming write path ~2x vs plain stores (fill kernel hits 7 TB/s plain).
__global__ __launch_bounds__(256) void scatter_kernel(const float* __restrict__ x,
                                                      const int2* __restrict__ smap,
                                                      const int* __restrict__ loads_i,
                                                      float* __restrict__ out_data,
                                                      float* __restrict__ out_tags) {
    const int tid = threadIdx.x;
    const int row0 = blockIdx.x * 4;
    const int base = tid * 8;
#pragma unroll
    for (int k = 0; k < 4; ++k) {
        const int row = row0 + k;
        const int e = row >> 12;
        const int r = row & (T_TOK - 1);
        float* orow = out_data + (size_t)row * D_DIM;
        if (r >= loads_i[e]) {
            if (tid == 0) out_tags[row] = -1.0f;
            const f32x4 z = {0.f, 0.f, 0.f, 0.f};
            *reinterpret_cast<f32x4*>(orow + base) = z;
            *reinterpret_cast<f32x4*>(orow + base + 4) = z;
        } else {
            const int2 sg = smap[row];
            const int src = sg.x;
            const float g = __int_as_float(sg.y);
            if (tid == 0) out_tags[row] = (float)src;
            const float* xr = x + (size_t)src * D_DIM;
            f32x4 a = *reinterpret_cast<const f32x4*>(xr + base);
            f32x4 b = *reinterpret_cast<const f32x4*>(xr + base + 4);
            a *= g;
            b *= g;
            *reinterpret_cast<f32x4*>(orow + base) = a;
            *reinterpret_cast<f32x4*>(orow + base + 4) = b;
        }
    }
}

extern "C" void kernel_launch(void* const* d_in, const int* in_sizes, int n_in,
                              void* d_out, int out_size, void* d_ws, size_t ws_size,
                              hipStream_t stream) {
    const float* x  = (const float*)d_in[0];
    const float* Wg = (const float*)d_in[1];

    float* out       = (float*)d_out;
    float* out_data  = out;
    float* out_tags  = out + (size_t)E_EXP * T_TOK * D_DIM;
    float* out_loads = out_tags + E_EXP * T_TOK;

    char* ws = (char*)d_ws;
    TokRec* recs    = (TokRec*)ws;                         // 64 KiB
    int2*   smap    = (int2*)(ws + 65536);                 // 256 KiB
    int*    loads_i = (int*)(ws + 65536 + 262144);         // 32 B

    gating_kernel<<<T_TOK / 4, 256, 0, stream>>>(x, Wg, recs);
    scan_kernel<<<1, 256, 0, stream>>>(recs, smap, loads_i, out_loads);
    scatter_kernel<<<E_EXP * T_TOK / 4, 256, 0, stream>>>(x, smap, loads_i, out_data, out_tags);
}

// Round 5
// 80.302 us; speedup vs baseline: 1.9705x; 1.1646x over previous
//
#include <hip/hip_runtime.h>
#include <math.h>

#define T_TOK 4096
#define D_DIM 2048
#define E_EXP 8

typedef float f32x4 __attribute__((ext_vector_type(4)));

struct TokRec { int e0, e1; float g0, g1; };

// ---------------- Kernel 0: transpose Wg[d][e] -> WgT[e][d] ------------------
// 64 KB one-time; makes gating's Wg loads lane-coalesced.
__global__ __launch_bounds__(256) void transpose_kernel(const float* __restrict__ Wg,
                                                        float* __restrict__ WgT) {
    const int d = blockIdx.x * 256 + threadIdx.x;   // 8 blocks x 256 = 2048
    const float4 a = *reinterpret_cast<const float4*>(Wg + (size_t)d * E_EXP);
    const float4 b = *reinterpret_cast<const float4*>(Wg + (size_t)d * E_EXP + 4);
    WgT[0 * D_DIM + d] = a.x;
    WgT[1 * D_DIM + d] = a.y;
    WgT[2 * D_DIM + d] = a.z;
    WgT[3 * D_DIM + d] = a.w;
    WgT[4 * D_DIM + d] = b.x;
    WgT[5 * D_DIM + d] = b.y;
    WgT[6 * D_DIM + d] = b.z;
    WgT[7 * D_DIM + d] = b.w;
}

// ---------------- Kernel 1: gating (logits -> softmax -> top2) --------------
// One wave (64 lanes) per token. fp64 accumulation so routing decisions match
// the reference exactly. WgT layout: per-expert rows, so each of the 8 Wg
// loads per iteration is a fully-coalesced float4 (R4 fix: the [d][e] layout
// cost 64 L1 transactions per load instruction).
__global__ __launch_bounds__(256) void gating_kernel(const float* __restrict__ x,
                                                     const float* __restrict__ WgT,
                                                     TokRec* __restrict__ recs) {
    const int wave = threadIdx.x >> 6;
    const int lane = threadIdx.x & 63;
    const int t = blockIdx.x * 4 + wave;
    const float* xr = x + (size_t)t * D_DIM;

    double acc[E_EXP];
#pragma unroll
    for (int e = 0; e < E_EXP; ++e) acc[e] = 0.0;

#pragma unroll
    for (int i = 0; i < D_DIM / 256; ++i) {
        const int d = i * 256 + lane * 4;
        const f32x4 xv = *reinterpret_cast<const f32x4*>(xr + d);
#pragma unroll
        for (int e = 0; e < E_EXP; ++e) {
            const f32x4 w = *reinterpret_cast<const f32x4*>(WgT + (size_t)e * D_DIM + d);
            acc[e] += (double)xv.x * (double)w.x + (double)xv.y * (double)w.y
                    + (double)xv.z * (double)w.z + (double)xv.w * (double)w.w;
        }
    }
#pragma unroll
    for (int e = 0; e < E_EXP; ++e) {
        double v = acc[e];
#pragma unroll
        for (int off = 32; off > 0; off >>= 1) v += __shfl_xor(v, off, 64);
        acc[e] = v;
    }
    if (lane == 0) {
        double m = acc[0];
#pragma unroll
        for (int e = 1; e < E_EXP; ++e) m = (acc[e] > m) ? acc[e] : m;
        double Z = 0.0;
#pragma unroll
        for (int e = 0; e < E_EXP; ++e) Z += exp(acc[e] - m);
        int e0 = 0;
#pragma unroll
        for (int e = 1; e < E_EXP; ++e) if (acc[e] > acc[e0]) e0 = e;
        int e1 = (e0 == 0) ? 1 : 0;
#pragma unroll
        for (int e = 0; e < E_EXP; ++e) if (e != e0 && acc[e] > acc[e1]) e1 = e;
        TokRec r;
        r.e0 = e0; r.e1 = e1;
        r.g0 = (float)(exp(acc[e0] - m) / Z);
        r.g1 = (float)(exp(acc[e1] - m) / Z);
        recs[t] = r;
    }
}

// ---------------- Kernel 2: single-block scan -> positions ------------------
__global__ __launch_bounds__(256) void scan_kernel(const TokRec* __restrict__ recs,
                                                   int2* __restrict__ smap,
                                                   int* __restrict__ loads_i,
                                                   float* __restrict__ loads_out) {
    __shared__ uint4 sb[256];
    __shared__ int offlds[256 * 8];
    const int tid = threadIdx.x;

    const int t0 = tid * 16;
    unsigned long long c = 0ULL;
    TokRec rl[16];
    for (int k = 0; k < 16; ++k) {
        rl[k] = recs[t0 + k];
        c += 1ULL << (rl[k].e0 * 8);
        c += 1ULL << (rl[k].e1 * 8);
    }
    uint4 v;
    v.x = (unsigned)((c       ) & 0xFF) | ((unsigned)((c >>  8) & 0xFF) << 16);
    v.y = (unsigned)((c >> 16 ) & 0xFF) | ((unsigned)((c >> 24) & 0xFF) << 16);
    v.z = (unsigned)((c >> 32 ) & 0xFF) | ((unsigned)((c >> 40) & 0xFF) << 16);
    v.w = (unsigned)((c >> 48 ) & 0xFF) | ((unsigned)((c >> 56) & 0xFF) << 16);
    const uint4 own = v;
    sb[tid] = v;
    for (int d = 1; d < 256; d <<= 1) {
        __syncthreads();
        uint4 o = make_uint4(0u, 0u, 0u, 0u);
        if (tid >= d) o = sb[tid - d];
        __syncthreads();
        v.x += o.x; v.y += o.y; v.z += o.z; v.w += o.w;
        sb[tid] = v;
    }
    __syncthreads();
    const uint4 tot = sb[255];

    offlds[tid * 8 + 0] = (int)((v.x - own.x) & 0xFFFF);
    offlds[tid * 8 + 1] = (int)((v.x - own.x) >> 16);
    offlds[tid * 8 + 2] = (int)((v.y - own.y) & 0xFFFF);
    offlds[tid * 8 + 3] = (int)((v.y - own.y) >> 16);
    offlds[tid * 8 + 4] = (int)((v.z - own.z) & 0xFFFF);
    offlds[tid * 8 + 5] = (int)((v.z - own.z) >> 16);
    offlds[tid * 8 + 6] = (int)((v.w - own.w) & 0xFFFF);
    offlds[tid * 8 + 7] = (int)((v.w - own.w) >> 16);

    if (tid < 8) {
        unsigned comp = (tid < 2) ? tot.x : (tid < 4) ? tot.y : (tid < 6) ? tot.z : tot.w;
        unsigned val = (tid & 1) ? (comp >> 16) : (comp & 0xFFFF);
        loads_i[tid] = (int)val;
        loads_out[tid] = (float)val;   // loads output written as float32
    }

    const int obase = tid * 8;
    for (int k = 0; k < 16; ++k) {
        const TokRec r = rl[k];
        const int tok = t0 + k;
        int d0 = offlds[obase + r.e0]++;
        smap[r.e0 * T_TOK + d0] = make_int2(tok, __float_as_int(r.g0));
        int d1 = offlds[obase + r.e1]++;
        smap[r.e1 * T_TOK + d1] = make_int2(tok, __float_as_int(r.g1));
    }
}

// ---------------- Kernel 3: full out_data fill + tags -----------------------
// 4 rows per block; plain vector stores (NT stores regressed 2x in R3).
__global__ __launch_bounds__(256) void scatter_kernel(const float* __restrict__ x,
                                                      const int2* __restrict__ smap,
                                                      const int* __restrict__ loads_i,
                                                      float* __restrict__ out_data,
                                                      float* __restrict__ out_tags) {
    const int tid = threadIdx.x;
    const int row0 = blockIdx.x * 4;
    const int base = tid * 8;
    // all 4 rows of this block share at most 2 experts; preload both counts
    const int e_first = row0 >> 12;
    const int e_last = (row0 + 3) >> 12;
    const int lf = loads_i[e_first];
    const int ll = (e_last != e_first) ? loads_i[e_last] : lf;
#pragma unroll
    for (int k = 0; k < 4; ++k) {
        const int row = row0 + k;
        const int e = row >> 12;
        const int r = row & (T_TOK - 1);
        const int le = (e == e_first) ? lf : ll;
        float* orow = out_data + (size_t)row * D_DIM;
        if (r >= le) {
            if (tid == 0) out_tags[row] = -1.0f;
            const f32x4 z = {0.f, 0.f, 0.f, 0.f};
            *reinterpret_cast<f32x4*>(orow + base) = z;
            *reinterpret_cast<f32x4*>(orow + base + 4) = z;
        } else {
            const int2 sg = smap[row];
            const int src = sg.x;
            const float g = __int_as_float(sg.y);
            if (tid == 0) out_tags[row] = (float)src;
            const float* xr = x + (size_t)src * D_DIM;
            f32x4 a = *reinterpret_cast<const f32x4*>(xr + base);
            f32x4 b = *reinterpret_cast<const f32x4*>(xr + base + 4);
            a *= g;
            b *= g;
            *reinterpret_cast<f32x4*>(orow + base) = a;
            *reinterpret_cast<f32x4*>(orow + base + 4) = b;
        }
    }
}

extern "C" void kernel_launch(void* const* d_in, const int* in_sizes, int n_in,
                              void* d_out, int out_size, void* d_ws, size_t ws_size,
                              hipStream_t stream) {
    const float* x  = (const float*)d_in[0];
    const float* Wg = (const float*)d_in[1];

    float* out       = (float*)d_out;
    float* out_data  = out;
    float* out_tags  = out + (size_t)E_EXP * T_TOK * D_DIM;
    float* out_loads = out_tags + E_EXP * T_TOK;

    char* ws = (char*)d_ws;
    TokRec* recs    = (TokRec*)ws;                         // 64 KiB @ 0
    int2*   smap    = (int2*)(ws + 65536);                 // 256 KiB
    int*    loads_i = (int*)(ws + 65536 + 262144);         // 32 B
    float*  WgT     = (float*)(ws + 65536 + 262144 + 1024);// 64 KiB

    transpose_kernel<<<D_DIM / 256, 256, 0, stream>>>(Wg, WgT);
    gating_kernel<<<T_TOK / 4, 256, 0, stream>>>(x, WgT, recs);
    scan_kernel<<<1, 256, 0, stream>>>(recs, smap, loads_i, out_loads);
    scatter_kernel<<<E_EXP * T_TOK / 4, 256, 0, stream>>>(x, smap, loads_i, out_data, out_tags);
}